// Round 8
// baseline (410.959 us; speedup 1.0000x reference)
//
#include <hip/hip_runtime.h>
#include <hip/hip_bf16.h>
#include <stdint.h>

typedef __bf16 bf16_t;
typedef __bf16 bf16x8 __attribute__((ext_vector_type(8)));
typedef float  f32x4  __attribute__((ext_vector_type(4)));

#define BM 128
#define BN 128
#define BK 64
#define NTHREADS 256

// ---------------- Kernel 1: global absmax of weight ----------------
__global__ void k_absmax(const float* __restrict__ w, unsigned int* __restrict__ out_bits, int n4) {
    int i = blockIdx.x * blockDim.x + threadIdx.x;
    int stride = gridDim.x * blockDim.x;
    const float4* w4 = (const float4*)w;
    float m = 0.0f;
    for (; i < n4; i += stride) {
        float4 v = w4[i];
        m = fmaxf(m, fmaxf(fmaxf(fabsf(v.x), fabsf(v.y)), fmaxf(fabsf(v.z), fabsf(v.w))));
    }
    #pragma unroll
    for (int off = 32; off; off >>= 1)
        m = fmaxf(m, __shfl_xor(m, off));
    if ((threadIdx.x & 63) == 0)
        atomicMax(out_bits, __float_as_uint(m));  // values >= 0: uint order == float order
}

// ---------------- e4m3fn round-to-nearest-even (positive inputs, <= 448) ----------------
__device__ __forceinline__ float e4m3_rne(float v) {
    if (v < 0.015625f) {                 // subnormal range: quantum 2^-9
        return rintf(v * 512.0f) * (1.0f / 512.0f);
    }
    unsigned int u = __float_as_uint(v);
    unsigned int keep = u >> 20;         // sign+exp+3 mantissa bits
    unsigned int r = u & 0xFFFFFu;       // 20 dropped bits
    if (r > 0x80000u || (r == 0x80000u && (keep & 1u))) keep++;
    return __uint_as_float(keep << 20);
}

// ---------------- Kernel 2: NVFP4 fake-quantize weight -> bf16 ----------------
__global__ void k_quantize(const float* __restrict__ w, bf16_t* __restrict__ wq,
                           const unsigned int* __restrict__ maxbits, int nblk) {
    int t = blockIdx.x * blockDim.x + threadIdx.x;
    if (t >= nblk) return;
    float gmax = __uint_as_float(*maxbits);
    float gs = 2688.0f / gmax;                      // (6*448)/max|w|, fp32
    const float4* w4 = (const float4*)w + (size_t)t * 4;
    float4 v0 = w4[0], v1 = w4[1], v2 = w4[2], v3 = w4[3];
    float vv[16];
    vv[0]=v0.x; vv[1]=v0.y; vv[2]=v0.z; vv[3]=v0.w;
    vv[4]=v1.x; vv[5]=v1.y; vv[6]=v1.z; vv[7]=v1.w;
    vv[8]=v2.x; vv[9]=v2.y; vv[10]=v2.z; vv[11]=v2.w;
    vv[12]=v3.x; vv[13]=v3.y; vv[14]=v3.z; vv[15]=v3.w;
    float bmax = 0.0f;
    #pragma unroll
    for (int j = 0; j < 16; ++j) bmax = fmaxf(bmax, fabsf(vv[j]));
    float s_decb = bmax / 6.0f;
    float xs_in  = fminf(s_decb * gs, 448.0f);      // clip (always >= 0)
    float xs_f   = e4m3_rne(xs_in);
    float s_encb = gs / fmaxf(xs_f, 1e-12f);
    float dscale = xs_f / gs;
    bf16x8 o0, o1;
    #pragma unroll
    for (int j = 0; j < 16; ++j) {
        float xsc = vv[j] * s_encb;
        float a = fabsf(xsc);
        float mag = (a <= 0.25f) ? 0.0f
                  : (a <  0.75f) ? 0.5f
                  : (a <= 1.25f) ? 1.0f
                  : (a <  1.75f) ? 1.5f
                  : (a <= 2.5f ) ? 2.0f
                  : (a <  3.5f ) ? 3.0f
                  : (a <= 5.0f ) ? 4.0f : 6.0f;
        float sgn = __builtin_copysignf(1.0f, xsc);
        float val = (sgn * mag) * dscale;
        if (j < 8) o0[j] = (bf16_t)val; else o1[j - 8] = (bf16_t)val;
    }
    *(bf16x8*)(wq + (size_t)t * 16)     = o0;
    *(bf16x8*)(wq + (size_t)t * 16 + 8) = o1;
}

// ---------------- Kernel 3: x fp32 -> bf16 ----------------
__global__ void k_cvt_x(const float* __restrict__ x, bf16_t* __restrict__ xb, long n8) {
    long i = blockIdx.x * (long)blockDim.x + threadIdx.x;
    long stride = (long)gridDim.x * blockDim.x;
    const float4* x4 = (const float4*)x;
    for (; i < n8; i += stride) {
        float4 a = x4[2 * i], b = x4[2 * i + 1];
        bf16x8 o;
        o[0] = (bf16_t)a.x; o[1] = (bf16_t)a.y; o[2] = (bf16_t)a.z; o[3] = (bf16_t)a.w;
        o[4] = (bf16_t)b.x; o[5] = (bf16_t)b.y; o[6] = (bf16_t)b.z; o[7] = (bf16_t)b.w;
        *(bf16x8*)(xb + i * 8) = o;
    }
}

// ---------------- helpers ----------------
__device__ __forceinline__ void BARRIER() {
    asm volatile("" ::: "memory");
    __builtin_amdgcn_s_barrier();
    asm volatile("" ::: "memory");
}

__device__ __forceinline__ void gload16(const bf16_t* g, bf16_t* l) {
    __builtin_amdgcn_global_load_lds(
        (const __attribute__((address_space(1))) unsigned int*)g,
        (__attribute__((address_space(3))) unsigned int*)l,
        16, 0, 0);
}

// ---- Kernel 4: 128x128, BK=64, 8-phase counted-vmcnt schedule, 2 blocks/CU ----
// LDS tile: row r (0..127) holds 8 granules of 16B; logical granule g at phys g ^ (r&7).
// Half-tile h = rows {h*32..h*32+31} U {64+h*32..64+h*32+31} (aligns with quadrant retirement).
__global__ __launch_bounds__(NTHREADS, 2) void k_gemm(
        const bf16_t* __restrict__ A,   // [M][K]
        const bf16_t* __restrict__ Bt,  // [N][K]
        const float*  __restrict__ bias,
        float* __restrict__ C, int M, int N, int K) {
    __shared__ __align__(16) bf16_t sA[2][BM * BK];   // 2 x 16 KB
    __shared__ __align__(16) bf16_t sB[2][BN * BK];   // 2 x 16 KB  -> 64 KB, 2 blocks/CU

    // XCD-aware bijective swizzle (gridDim.x % 8 == 0 here)
    int bid = blockIdx.x;
    int cpx = gridDim.x >> 3;
    int swz = (bid & 7) * cpx + (bid >> 3);
    int nbn = N / BN;
    int m0 = (swz / nbn) * BM, n0 = (swz % nbn) * BN;

    int tid  = threadIdx.x;
    int lane = tid & 63;
    int w    = tid >> 6;          // 4 waves: 2 (M) x 2 (N); wave tile 64x64
    int wr   = w >> 1, wc = w & 1;
    int fr15 = lane & 15;
    int kg   = lane >> 4;         // k-granule within 32-k slot

    // ---- staging: half-tile h -> 512 granules over 256 threads (2 loads/thread).
    // pf = l*256 + tid; rowin = tid>>3 (0..31); row = l*64 + h*32 + rowin; pg = tid&7.
    int rowin = tid >> 3;
    int pg    = tid & 7;
    int gsw   = pg ^ (rowin & 7);              // inverse swizzle on GLOBAL source (rule #21)
    int gstg[2], lstg[2];
    #pragma unroll
    for (int l = 0; l < 2; ++l) {
        gstg[l] = (l * 64 + rowin) * K + gsw * 8;   // + h*32*K + kt at call
        lstg[l] = (l * 64 + rowin) * 64 + pg * 8;   // + h*2048 at call
    }
    const bf16_t* Ab = A  + (size_t)m0 * K;
    const bf16_t* Bb = Bt + (size_t)n0 * K;

#define STG(SX, Xb, BUF, H, KT) do {                                               \
        gload16(Xb + (H) * 32 * K + gstg[0] + (KT), &SX[BUF][(H) * 2048 + lstg[0]]); \
        gload16(Xb + (H) * 32 * K + gstg[1] + (KT), &SX[BUF][(H) * 2048 + lstg[1]]); \
    } while (0)

    // ---- read offsets: rows = base + q*16 + fr15 (base mult of 8) -> row&7 = fr15&7
    // phys granule (ks*4+kg) ^ (fr15&7) is q/j-invariant.
    int f01 = fr15 & 3, f2 = (fr15 >> 2) & 1;
    int pgr0 = 4 * (0 ^ f2) + (kg ^ f01);
    int pgr1 = 4 * (1 ^ f2) + (kg ^ f01);
    int baseA0 = (wr * 64 + fr15) * 64 + pgr0 * 8;
    int baseA1 = (wr * 64 + fr15) * 64 + pgr1 * 8;
    int baseB0 = (wc * 64 + fr15) * 64 + pgr0 * 8;
    int baseB1 = (wc * 64 + fr15) * 64 + pgr1 * 8;

    f32x4 acc[4][4] = {};
    bf16x8 bfr[4][2];

    const int NT = K / BK;        // 64 tiles
    const int ITERS = NT / 2;     // 32

    // ---- prologue: tile0 (all 4 halves) -> buf0; tile1 B(2h) + A(h0) -> buf1 (6 in flight)
    STG(sB, Bb, 0, 0, 0);  STG(sB, Bb, 0, 1, 0);
    STG(sA, Ab, 0, 0, 0);  STG(sA, Ab, 0, 1, 0);
    STG(sB, Bb, 1, 0, BK); STG(sB, Bb, 1, 1, BK);
    STG(sA, Ab, 1, 0, BK);
    asm volatile("s_waitcnt vmcnt(6)" ::: "memory");
    BARRIER();

#define RDA(PA, Q, AK0, AK1)                                           \
    bf16x8 AK0 = *(const bf16x8*)((PA) + baseA0 + (Q) * 1024);          \
    bf16x8 AK1 = *(const bf16x8*)((PA) + baseA1 + (Q) * 1024);

#define RDB(PB) do {                                                   \
        _Pragma("unroll")                                              \
        for (int j = 0; j < 4; ++j) {                                  \
            bfr[j][0] = *(const bf16x8*)((PB) + baseB0 + j * 1024);    \
            bfr[j][1] = *(const bf16x8*)((PB) + baseB1 + j * 1024);    \
        }                                                              \
    } while (0)

// 8 MFMA: k0-quartet then k1-quartet (breaks back-to-back RAW pairs)
#define MF8(Q, AK0, AK1) do {                                                                      \
        __builtin_amdgcn_s_setprio(1);                                                             \
        _Pragma("unroll")                                                                          \
        for (int j = 0; j < 4; ++j)                                                                \
            acc[Q][j] = __builtin_amdgcn_mfma_f32_16x16x32_bf16(AK0, bfr[j][0], acc[Q][j], 0, 0, 0); \
        _Pragma("unroll")                                                                          \
        for (int j = 0; j < 4; ++j)                                                                \
            acc[Q][j] = __builtin_amdgcn_mfma_f32_16x16x32_bf16(AK1, bfr[j][1], acc[Q][j], 0, 0, 0); \
        __builtin_amdgcn_s_setprio(0);                                                             \
    } while (0)

#define LGKM0() asm volatile("s_waitcnt lgkmcnt(0)" ::: "memory")

    for (int it = 0; it < ITERS; ++it) {
        const bool nl = (it + 1 < ITERS);
        const int ktB1 = (2 * it + 1) * BK;   // current buf1 tile (its A-h1 staged at P0)
        const int kt2  = (2 * it + 2) * BK;   // tile -> buf0
        const int kt3  = (2 * it + 3) * BK;   // tile -> buf1

        // P0: Q0 buf0; read B(buf0)+A-q0 (10 reads); stage A(t_b)h1 -> buf1
        {
            RDA(sA[0], 0, a0, a1);
            RDB(sB[0]);
            STG(sA, Ab, 1, 1, ktB1);
            BARRIER(); LGKM0();
            MF8(0, a0, a1);
            BARRIER();
        }
        // P1: Q1 buf0; stage B(t+2)h0 -> buf0  (buf0-B retired at P0)
        {
            RDA(sA[0], 1, a0, a1);
            if (nl) STG(sB, Bb, 0, 0, kt2);
            BARRIER(); LGKM0();
            MF8(1, a0, a1);
            BARRIER();
        }
        // P2: Q2 buf0; stage B(t+2)h1 -> buf0
        {
            RDA(sA[0], 2, a0, a1);
            if (nl) STG(sB, Bb, 0, 1, kt2);
            BARRIER(); LGKM0();
            MF8(2, a0, a1);
            BARRIER();
        }
        // P3: Q3 buf0; stage A(t+2)h0 -> buf0 (buf0-A h0 = q0,q1 retired at P1);
        //     tail vmcnt publishes buf1 tile
        {
            RDA(sA[0], 3, a0, a1);
            if (nl) STG(sA, Ab, 0, 0, kt2);
            BARRIER(); LGKM0();
            MF8(3, a0, a1);
            if (nl) { asm volatile("s_waitcnt vmcnt(6)" ::: "memory"); }
            else    { asm volatile("s_waitcnt vmcnt(0)" ::: "memory"); }
            BARRIER();
        }
        // P4: Q0 buf1; read B(buf1)+A-q0; stage A(t+2)h1 -> buf0 (h1 = q2,q3 retired at P3)
        {
            RDA(sA[1], 0, a0, a1);
            RDB(sB[1]);
            if (nl) STG(sA, Ab, 0, 1, kt2);
            BARRIER(); LGKM0();
            MF8(0, a0, a1);
            BARRIER();
        }
        // P5: Q1 buf1; stage B(t+3)h0 -> buf1 (buf1-B retired at P4)
        {
            RDA(sA[1], 1, a0, a1);
            if (nl) STG(sB, Bb, 1, 0, kt3);
            BARRIER(); LGKM0();
            MF8(1, a0, a1);
            BARRIER();
        }
        // P6: Q2 buf1; stage B(t+3)h1 -> buf1
        {
            RDA(sA[1], 2, a0, a1);
            if (nl) STG(sB, Bb, 1, 1, kt3);
            BARRIER(); LGKM0();
            MF8(2, a0, a1);
            BARRIER();
        }
        // P7: Q3 buf1; stage A(t+3)h0 -> buf1 (buf1-A h0 retired at P5);
        //     tail vmcnt publishes buf0 tile (t+2)
        {
            RDA(sA[1], 3, a0, a1);
            if (nl) STG(sA, Ab, 1, 0, kt3);
            BARRIER(); LGKM0();
            MF8(3, a0, a1);
            if (nl) { asm volatile("s_waitcnt vmcnt(6)" ::: "memory"); }
            BARRIER();
        }
    }
    asm volatile("s_waitcnt vmcnt(0)" ::: "memory");  // drain before epilogue

    // epilogue: C/D mapping col = lane&15, row = (lane>>4)*4 + reg
    int crow = (lane >> 4) * 4;
    int ccol = lane & 15;
    float bv[4];
    #pragma unroll
    for (int j = 0; j < 4; ++j) bv[j] = bias[n0 + wc * 64 + j * 16 + ccol];
    #pragma unroll
    for (int q = 0; q < 4; ++q) {
        size_t mrow = (size_t)(m0 + wr * 64 + q * 16 + crow);
        #pragma unroll
        for (int j = 0; j < 4; ++j) {
            float* cp = C + mrow * N + (n0 + wc * 64 + j * 16 + ccol);
            #pragma unroll
            for (int r = 0; r < 4; ++r)
                cp[(size_t)r * N] = acc[q][j][r] + bv[j];
        }
    }
#undef STG
#undef RDA
#undef RDB
#undef MF8
#undef LGKM0
}

extern "C" void kernel_launch(void* const* d_in, const int* in_sizes, int n_in,
                              void* d_out, int out_size, void* d_ws, size_t ws_size,
                              hipStream_t stream) {
    const float* x    = (const float*)d_in[0];
    const float* wgt  = (const float*)d_in[1];
    const float* bias = (const float*)d_in[2];
    float* out = (float*)d_out;

    const int N = in_sizes[2];            // 4096 (OUT)
    const int K = in_sizes[1] / N;        // 4096 (IN)
    const int M = in_sizes[0] / K;        // 8192 (B*S)

    unsigned int* maxbits = (unsigned int*)d_ws;
    bf16_t* wq = (bf16_t*)((char*)d_ws + 256);
    bf16_t* xb = (bf16_t*)((char*)d_ws + 256 + (size_t)N * K * sizeof(bf16_t));

    hipMemsetAsync(d_ws, 0, 256, stream);
    k_absmax<<<512, 256, 0, stream>>>(wgt, maxbits, N * K / 4);
    int nblk = N * K / 16;
    k_quantize<<<(nblk + 255) / 256, 256, 0, stream>>>(wgt, wq, maxbits, nblk);
    long n8 = (long)M * K / 8;
    k_cvt_x<<<2048, 256, 0, stream>>>(x, xb, n8);
    dim3 grid((M / BM) * (N / BN));
    k_gemm<<<grid, NTHREADS, 0, stream>>>(xb, wq, bias, out, M, N, K);
}

// Round 9
// 331.342 us; speedup vs baseline: 1.2403x; 1.2403x over previous
//
#include <hip/hip_runtime.h>
#include <hip/hip_bf16.h>
#include <stdint.h>

typedef __bf16 bf16_t;
typedef __bf16 bf16x8 __attribute__((ext_vector_type(8)));
typedef float  f32x4  __attribute__((ext_vector_type(4)));

#define BM 256
#define BN 256
#define BK 64
#define NTHREADS 512

// ---------------- Kernel 1: global absmax of weight ----------------
__global__ void k_absmax(const float* __restrict__ w, unsigned int* __restrict__ out_bits, int n4) {
    int i = blockIdx.x * blockDim.x + threadIdx.x;
    int stride = gridDim.x * blockDim.x;
    const float4* w4 = (const float4*)w;
    float m = 0.0f;
    for (; i < n4; i += stride) {
        float4 v = w4[i];
        m = fmaxf(m, fmaxf(fmaxf(fabsf(v.x), fabsf(v.y)), fmaxf(fabsf(v.z), fabsf(v.w))));
    }
    #pragma unroll
    for (int off = 32; off; off >>= 1)
        m = fmaxf(m, __shfl_xor(m, off));
    if ((threadIdx.x & 63) == 0)
        atomicMax(out_bits, __float_as_uint(m));  // values >= 0: uint order == float order
}

// ---------------- e4m3fn round-to-nearest-even (positive inputs, <= 448) ----------------
__device__ __forceinline__ float e4m3_rne(float v) {
    if (v < 0.015625f) {                 // subnormal range: quantum 2^-9
        return rintf(v * 512.0f) * (1.0f / 512.0f);
    }
    unsigned int u = __float_as_uint(v);
    unsigned int keep = u >> 20;         // sign+exp+3 mantissa bits
    unsigned int r = u & 0xFFFFFu;       // 20 dropped bits
    if (r > 0x80000u || (r == 0x80000u && (keep & 1u))) keep++;
    return __uint_as_float(keep << 20);
}

// ---------------- Kernel 2: NVFP4 fake-quantize weight -> bf16 ----------------
__global__ void k_quantize(const float* __restrict__ w, bf16_t* __restrict__ wq,
                           const unsigned int* __restrict__ maxbits, int nblk) {
    int t = blockIdx.x * blockDim.x + threadIdx.x;
    if (t >= nblk) return;
    float gmax = __uint_as_float(*maxbits);
    float gs = 2688.0f / gmax;                      // (6*448)/max|w|, fp32
    const float4* w4 = (const float4*)w + (size_t)t * 4;
    float4 v0 = w4[0], v1 = w4[1], v2 = w4[2], v3 = w4[3];
    float vv[16];
    vv[0]=v0.x; vv[1]=v0.y; vv[2]=v0.z; vv[3]=v0.w;
    vv[4]=v1.x; vv[5]=v1.y; vv[6]=v1.z; vv[7]=v1.w;
    vv[8]=v2.x; vv[9]=v2.y; vv[10]=v2.z; vv[11]=v2.w;
    vv[12]=v3.x; vv[13]=v3.y; vv[14]=v3.z; vv[15]=v3.w;
    float bmax = 0.0f;
    #pragma unroll
    for (int j = 0; j < 16; ++j) bmax = fmaxf(bmax, fabsf(vv[j]));
    float s_decb = bmax / 6.0f;
    float xs_in  = fminf(s_decb * gs, 448.0f);      // clip (always >= 0)
    float xs_f   = e4m3_rne(xs_in);
    float s_encb = gs / fmaxf(xs_f, 1e-12f);
    float dscale = xs_f / gs;
    bf16x8 o0, o1;
    #pragma unroll
    for (int j = 0; j < 16; ++j) {
        float xsc = vv[j] * s_encb;
        float a = fabsf(xsc);
        float mag = (a <= 0.25f) ? 0.0f
                  : (a <  0.75f) ? 0.5f
                  : (a <= 1.25f) ? 1.0f
                  : (a <  1.75f) ? 1.5f
                  : (a <= 2.5f ) ? 2.0f
                  : (a <  3.5f ) ? 3.0f
                  : (a <= 5.0f ) ? 4.0f : 6.0f;
        float sgn = __builtin_copysignf(1.0f, xsc);
        float val = (sgn * mag) * dscale;
        if (j < 8) o0[j] = (bf16_t)val; else o1[j - 8] = (bf16_t)val;
    }
    *(bf16x8*)(wq + (size_t)t * 16)     = o0;
    *(bf16x8*)(wq + (size_t)t * 16 + 8) = o1;
}

// ---------------- Kernel 3: x fp32 -> bf16 ----------------
__global__ void k_cvt_x(const float* __restrict__ x, bf16_t* __restrict__ xb, long n8) {
    long i = blockIdx.x * (long)blockDim.x + threadIdx.x;
    long stride = (long)gridDim.x * blockDim.x;
    const float4* x4 = (const float4*)x;
    for (; i < n8; i += stride) {
        float4 a = x4[2 * i], b = x4[2 * i + 1];
        bf16x8 o;
        o[0] = (bf16_t)a.x; o[1] = (bf16_t)a.y; o[2] = (bf16_t)a.z; o[3] = (bf16_t)a.w;
        o[4] = (bf16_t)b.x; o[5] = (bf16_t)b.y; o[6] = (bf16_t)b.z; o[7] = (bf16_t)b.w;
        *(bf16x8*)(xb + i * 8) = o;
    }
}

// ---------------- helpers ----------------
__device__ __forceinline__ void BARRIER() {
    asm volatile("" ::: "memory");
    __builtin_amdgcn_s_barrier();
    asm volatile("" ::: "memory");
}

__device__ __forceinline__ void gload16(const bf16_t* g, bf16_t* l) {
    __builtin_amdgcn_global_load_lds(
        (const __attribute__((address_space(1))) unsigned int*)g,
        (__attribute__((address_space(3))) unsigned int*)l,
        16, 0, 0);
}

// ---- Kernel 4: 256x256, BK=64, 8-phase quadrant schedule (m201 form), vmcnt(6) ----
// LDS tile: row r (0..255) holds 8 granules of 16B; logical granule g at phys g ^ (r&7).
// A half-tile h: rows {l*128 + h*64 + r, r<64}  (aligns with m-half retirement)
// B half-tile h: rows {q*64  + h*32 + r, r<32}  (aligns with n-half retirement)
__global__ __launch_bounds__(NTHREADS, 2) void k_gemm(
        const bf16_t* __restrict__ A,   // [M][K]
        const bf16_t* __restrict__ Bt,  // [N][K]
        const float*  __restrict__ bias,
        float* __restrict__ C, int M, int N, int K) {
    __shared__ __align__(16) bf16_t sA[2][BM * BK];   // 2 x 32 KB
    __shared__ __align__(16) bf16_t sB[2][BN * BK];   // 2 x 32 KB  -> 128 KB

    // XCD-aware bijective swizzle (gridDim.x % 8 == 0 here)
    int bid = blockIdx.x;
    int cpx = gridDim.x >> 3;
    int swz = (bid & 7) * cpx + (bid >> 3);
    int nbn = N / BN;
    int m0 = (swz / nbn) * BM, n0 = (swz % nbn) * BN;

    int tid  = threadIdx.x;
    int lane = tid & 63;
    int w    = tid >> 6;          // 8 waves: 2 (M) x 4 (N); wave tile 128x64
    int wr   = w >> 2, wc = w & 3;
    int fr15 = lane & 15;
    int kg   = lane >> 4;

    // ---- staging precompute (inverse swizzle on GLOBAL source, rule #21) ----
    int rowin = tid >> 3;                      // 0..63
    int pg    = tid & 7;
    int gsw   = pg ^ (rowin & 7);              // rowin&7 == rB&7 below
    // A: granule pf = l*512 + tid -> row = l*128 + H*64 + rowin
    int gstg[2], lstg[2];
    #pragma unroll
    for (int l = 0; l < 2; ++l) {
        gstg[l] = (l * 128 + rowin) * K + gsw * 8;   // + H*64*K + kt at call
        lstg[l] = (l * 128 + rowin) * 64 + pg * 8;   // + H*4096 at call
    }
    // B: granule pf = l*512 + tid -> row_idx = l*64 + (tid>>3); q = row_idx>>5, r = row_idx&31
    int tq0 = tid >> 8;                         // 0..1
    int rB  = (tid >> 3) & 31;
    int gbstg[2], lbstg[2];
    #pragma unroll
    for (int l = 0; l < 2; ++l) {
        int q = l * 2 + tq0;
        gbstg[l] = (q * 64 + rB) * K + gsw * 8;      // + H*32*K + kt at call
        lbstg[l] = (q * 64 + rB) * 64 + pg * 8;      // + H*2048 at call
    }
    const bf16_t* Ab = A  + (size_t)m0 * K;
    const bf16_t* Bb = Bt + (size_t)n0 * K;

#define STGA(BUF, H, KT) do {                                                      \
        gload16(Ab + (H) * 64 * K + gstg[0] + (KT), &sA[BUF][(H) * 4096 + lstg[0]]); \
        gload16(Ab + (H) * 64 * K + gstg[1] + (KT), &sA[BUF][(H) * 4096 + lstg[1]]); \
    } while (0)
#define STGB(BUF, H, KT) do {                                                      \
        gload16(Bb + (H) * 32 * K + gbstg[0] + (KT), &sB[BUF][(H) * 2048 + lbstg[0]]); \
        gload16(Bb + (H) * 32 * K + gbstg[1] + (KT), &sB[BUF][(H) * 2048 + lbstg[1]]); \
    } while (0)

    // ---- read offsets: phys granule (ks*4+kg) ^ (fr15&7), q/frag-invariant ----
    int f01 = fr15 & 3, f2 = (fr15 >> 2) & 1;
    int pgr0 = 4 * (0 ^ f2) + (kg ^ f01);
    int pgr1 = 4 * (1 ^ f2) + (kg ^ f01);
    int baseA0 = (wr * 128 + fr15) * 64 + pgr0 * 8;
    int baseA1 = (wr * 128 + fr15) * 64 + pgr1 * 8;
    int baseB0 = (wc * 64  + fr15) * 64 + pgr0 * 8;
    int baseB1 = (wc * 64  + fr15) * 64 + pgr1 * 8;

    f32x4 acc[8][4] = {};
    bf16x8 afr[4][2];   // current m-half fragments (reused across 2 phases)
    bf16x8 bfr[4][2];   // all 4 n-fragments of current tile

    const int NT = K / BK;        // 64 tiles
    const int ITERS = NT / 2;     // 32

    // ---- prologue: tile0 (4 halves) -> buf0; tile1 B(2h)+A(h0) -> buf1; 6 in flight
    STGB(0, 0, 0);  STGB(0, 1, 0);
    STGA(0, 0, 0);  STGA(0, 1, 0);
    STGB(1, 0, BK); STGB(1, 1, BK);
    STGA(1, 0, BK);
    asm volatile("s_waitcnt vmcnt(6)" ::: "memory");
    BARRIER();

#define RDA4(PA, MH) do {                                                          \
        _Pragma("unroll")                                                          \
        for (int m = 0; m < 4; ++m) {                                              \
            afr[m][0] = *(const bf16x8*)((PA) + baseA0 + ((MH) * 4 + m) * 1024);   \
            afr[m][1] = *(const bf16x8*)((PA) + baseA1 + ((MH) * 4 + m) * 1024);   \
        }                                                                          \
    } while (0)

#define RDB2(PB, NH) do {                                                          \
        _Pragma("unroll")                                                          \
        for (int j = 0; j < 2; ++j) {                                              \
            bfr[(NH)*2+j][0] = *(const bf16x8*)((PB) + baseB0 + ((NH)*2+j) * 1024);\
            bfr[(NH)*2+j][1] = *(const bf16x8*)((PB) + baseB1 + ((NH)*2+j) * 1024);\
        }                                                                          \
    } while (0)

// 16 MFMA for quadrant (MH,NH): 8 independent k0 ops, then 8 k1 (RAW distance 8)
#define MFQ(MH, NH) do {                                                                            \
        __builtin_amdgcn_s_setprio(1);                                                              \
        _Pragma("unroll")                                                                           \
        for (int n = 0; n < 2; ++n)                                                                 \
            _Pragma("unroll")                                                                       \
            for (int m = 0; m < 4; ++m)                                                             \
                acc[(MH)*4+m][(NH)*2+n] = __builtin_amdgcn_mfma_f32_16x16x32_bf16(                  \
                    afr[m][0], bfr[(NH)*2+n][0], acc[(MH)*4+m][(NH)*2+n], 0, 0, 0);                 \
        _Pragma("unroll")                                                                           \
        for (int n = 0; n < 2; ++n)                                                                 \
            _Pragma("unroll")                                                                       \
            for (int m = 0; m < 4; ++m)                                                             \
                acc[(MH)*4+m][(NH)*2+n] = __builtin_amdgcn_mfma_f32_16x16x32_bf16(                  \
                    afr[m][1], bfr[(NH)*2+n][1], acc[(MH)*4+m][(NH)*2+n], 0, 0, 0);                 \
        __builtin_amdgcn_s_setprio(0);                                                              \
    } while (0)

#define LGKM0() asm volatile("s_waitcnt lgkmcnt(0)" ::: "memory")

    for (int it = 0; it < ITERS; ++it) {
        const bool nl = (it + 1 < ITERS);
        const int ktB1 = (2 * it + 1) * BK;   // current buf1 tile (A-h1 staged at P0)
        const int kt2  = (2 * it + 2) * BK;   // tile -> buf0
        const int kt3  = (2 * it + 3) * BK;   // tile -> buf1

        // P0: quad(m0-3, n0-1) buf0; reads A-h0(8) + B-h0(4); stage A(buf1)h1
        RDA4(sA[0], 0); RDB2(sB[0], 0);
        STGA(1, 1, ktB1);
        BARRIER(); LGKM0(); MFQ(0, 0); BARRIER();

        // P1: quad(m0-3, n2-3); reads B-h1(4) [A reused]; stage B(t+2)h0 (retired P0)
        RDB2(sB[0], 1);
        if (nl) STGB(0, 0, kt2);
        BARRIER(); LGKM0(); MFQ(0, 1); BARRIER();

        // P2: quad(m4-7, n0-1); reads A-h1(8) [B reused]; stage B(t+2)h1 (retired P1)
        RDA4(sA[0], 1);
        if (nl) STGB(0, 1, kt2);
        BARRIER(); LGKM0(); MFQ(1, 0); BARRIER();

        // P3: quad(m4-7, n2-3); no reads; stage A(t+2)h0 (retired P0); publish buf1 tile
        if (nl) STGA(0, 0, kt2);
        BARRIER(); MFQ(1, 1);
        if (nl) { asm volatile("s_waitcnt vmcnt(6)" ::: "memory"); }
        else    { asm volatile("s_waitcnt vmcnt(0)" ::: "memory"); }
        BARRIER();

        // P4: quad(m0-3, n0-1) buf1; stage A(t+2)h1 (buf0 A-h1 retired P2)
        RDA4(sA[1], 0); RDB2(sB[1], 0);
        if (nl) STGA(0, 1, kt2);
        BARRIER(); LGKM0(); MFQ(0, 0); BARRIER();

        // P5: quad(m0-3, n2-3) buf1; stage B(t+3)h0 (buf1 B-h0 retired P4)
        RDB2(sB[1], 1);
        if (nl) STGB(1, 0, kt3);
        BARRIER(); LGKM0(); MFQ(0, 1); BARRIER();

        // P6: quad(m4-7, n0-1) buf1; stage B(t+3)h1 (retired P5)
        RDA4(sA[1], 1);
        if (nl) STGB(1, 1, kt3);
        BARRIER(); LGKM0(); MFQ(1, 0); BARRIER();

        // P7: quad(m4-7, n2-3) buf1; stage A(t+3)h0 (buf1 A-h0 retired P4); publish buf0
        if (nl) STGA(1, 0, kt3);
        BARRIER(); MFQ(1, 1);
        if (nl) { asm volatile("s_waitcnt vmcnt(6)" ::: "memory"); }
        BARRIER();
    }
    asm volatile("s_waitcnt vmcnt(0)" ::: "memory");  // drain before epilogue

    // epilogue: C/D mapping col = lane&15, row = (lane>>4)*4 + reg
    int crow = (lane >> 4) * 4;
    int ccol = lane & 15;
    float bv[4];
    #pragma unroll
    for (int j = 0; j < 4; ++j) bv[j] = bias[n0 + wc * 64 + j * 16 + ccol];
    #pragma unroll
    for (int i = 0; i < 8; ++i) {
        size_t mrow = (size_t)(m0 + wr * 128 + i * 16 + crow);
        #pragma unroll
        for (int j = 0; j < 4; ++j) {
            float* cp = C + mrow * N + (n0 + wc * 64 + j * 16 + ccol);
            #pragma unroll
            for (int r = 0; r < 4; ++r)
                cp[(size_t)r * N] = acc[i][j][r] + bv[j];
        }
    }
#undef STGA
#undef STGB
#undef RDA4
#undef RDB2
#undef MFQ
#undef LGKM0
}

extern "C" void kernel_launch(void* const* d_in, const int* in_sizes, int n_in,
                              void* d_out, int out_size, void* d_ws, size_t ws_size,
                              hipStream_t stream) {
    const float* x    = (const float*)d_in[0];
    const float* wgt  = (const float*)d_in[1];
    const float* bias = (const float*)d_in[2];
    float* out = (float*)d_out;

    const int N = in_sizes[2];            // 4096 (OUT)
    const int K = in_sizes[1] / N;        // 4096 (IN)
    const int M = in_sizes[0] / K;        // 8192 (B*S)

    unsigned int* maxbits = (unsigned int*)d_ws;
    bf16_t* wq = (bf16_t*)((char*)d_ws + 256);
    bf16_t* xb = (bf16_t*)((char*)d_ws + 256 + (size_t)N * K * sizeof(bf16_t));

    hipMemsetAsync(d_ws, 0, 256, stream);
    k_absmax<<<512, 256, 0, stream>>>(wgt, maxbits, N * K / 4);
    int nblk = N * K / 16;
    k_quantize<<<(nblk + 255) / 256, 256, 0, stream>>>(wgt, wq, maxbits, nblk);
    long n8 = (long)M * K / 8;
    k_cvt_x<<<2048, 256, 0, stream>>>(x, xb, n8);
    dim3 grid((M / BM) * (N / BN));
    k_gemm<<<grid, NTHREADS, 0, stream>>>(xb, wq, bias, out, M, N, K);
}